// Round 3
// baseline (20174.207 us; speedup 1.0000x reference)
//
#include <hip/hip_runtime.h>
#include <hip/hip_cooperative_groups.h>
#include <math.h>

#define NN 1024      // N
#define NB 64        // panel width
#define TT 128       // trailing SYRK tile
#define NSAMP 64     // n_mc
#define CGT 512      // coop block threads

#define CCONST  (-0.91893853320467274f)   // -0.5*log(2*pi)
#define LOG2PI  (1.8378770664093453f)

namespace cg = cooperative_groups;

__device__ __forceinline__ float bcastf(float v, int lane) {
    return __int_as_float(__builtin_amdgcn_readlane(__float_as_int(v), lane));
}
__device__ __forceinline__ float softplus_d(float v) {
    return (v > 20.f ? v : log1pf(expf(v))) + 1e-7f;
}
__device__ __forceinline__ float log_normal_f(float v, float mean, float s, float eps) {
    float d = v - mean;
    return -d * d / (2.f * s * s + eps) - logf(s) + CCONST;
}
__device__ __forceinline__ float log_lognormal_f(float v, float mean, float s) {
    float lv = logf(v);
    float d = lv - mean;
    return -d * d / (2.f * s * s + 1e-6f) - lv - logf(s) + CCONST;
}
__device__ __forceinline__ void fma4(float4& c, float a, const float4& b) {
    c.x = fmaf(a, b.x, c.x); c.y = fmaf(a, b.y, c.y);
    c.z = fmaf(a, b.z, c.z); c.w = fmaf(a, b.w, c.w);
}

// ---------------- per-sample scalars ----------------
__global__ void scal_kernel(const float* __restrict__ z,
    const float* qbm, const float* qbs, const float* qsm, const float* qss,
    const float* qem, const float* qes, const float* qzm, const float* qzs,
    const float* qnm, const float* qns, float* __restrict__ scal)
{
    int m = threadIdx.x;
    if (m >= NSAMP) return;
    float z0 = z[m*5+0], z1 = z[m*5+1], z2 = z[m*5+2], z3 = z[m*5+3], z4 = z[m*5+4];
    float spb = softplus_d(qbs[0]);
    float sps = softplus_d(qss[0]);
    float spe = softplus_d(qes[0]);
    float spz = softplus_d(qzs[0]);
    float spn = softplus_d(qns[0]);
    float sigma2 = expf(z0 * sps + qsm[0]);
    float beta   = z1 * spb + qbm[0];
    float eta    = expf(z2 * spe + qem[0]);
    float lsZ    = expf(z3 * spz + qzm[0]);
    float lsN    = expf(z4 * spn + qnm[0]);
    float s0 = softplus_d(sqrtf(logf(2.f)));
    float lp = log_normal_f(beta, 0.f, 1.f, 1e-5f)
             + log_lognormal_f(sigma2, 1.f, s0)
             + log_lognormal_f(eta,    1.f, s0)
             + log_lognormal_f(lsZ,    1.f, s0)
             + log_lognormal_f(lsN,    1.f, s0);
    float lq = log_normal_f(beta, qbm[0], spb, 1e-5f)
             + log_lognormal_f(sigma2, qsm[0], sps)
             + log_lognormal_f(eta,    qem[0], spe)
             + log_lognormal_f(lsZ,    qzm[0], spz)
             + log_lognormal_f(lsN,    qnm[0], spn);
    scal[m]           = sigma2;
    scal[NSAMP + m]   = eta;
    scal[2*NSAMP + m] = 1.f / lsZ;
    scal[3*NSAMP + m] = 1.f / lsN;
    scal[4*NSAMP + m] = beta;
    scal[5*NSAMP + m] = lp - lq;
}

// ---------------- covariance build (lower triangle) + bvec/stats init ----------------
__global__ __launch_bounds__(256)
void cov_kernel(float* __restrict__ cov, const float* __restrict__ scal,
                const float* __restrict__ x, const float* __restrict__ y,
                float* __restrict__ bvec, float* __restrict__ stats, int mbase)
{
    int i  = blockIdx.x;
    int ml = blockIdx.y;
    int m  = mbase + ml;
    if (threadIdx.x == 0) {
        bvec[(size_t)m * NN + i] = y[i] - scal[4*NSAMP + m];
        if (i == 0) { stats[2*m] = 0.f; stats[2*m+1] = 0.f; }
    }
    float sigma2 = scal[m];
    float eta    = scal[NSAMP + m];
    float ilZ    = scal[2*NSAMP + m];
    float ilN    = scal[3*NSAMP + m];
    float xi0 = x[2*i]   * ilZ;
    float xi1 = x[2*i+1] * ilN;
    float* row = cov + (size_t)ml * NN * NN + (size_t)i * NN;
    int j0 = threadIdx.x * 4;
    if (j0 > i) return;
    float4 xa = *(const float4*)(x + 2*j0);
    float4 xb = *(const float4*)(x + 2*j0 + 4);
    float v[4]; float d0, d1;
    d0 = xa.x*ilZ - xi0; d1 = xa.y*ilN - xi1; v[0] = eta*__expf(-0.5f*(d0*d0+d1*d1));
    d0 = xa.z*ilZ - xi0; d1 = xa.w*ilN - xi1; v[1] = eta*__expf(-0.5f*(d0*d0+d1*d1));
    d0 = xb.x*ilZ - xi0; d1 = xb.y*ilN - xi1; v[2] = eta*__expf(-0.5f*(d0*d0+d1*d1));
    d0 = xb.z*ilZ - xi0; d1 = xb.w*ilN - xi1; v[3] = eta*__expf(-0.5f*(d0*d0+d1*d1));
    #pragma unroll
    for (int q = 0; q < 4; ++q) if (j0 + q == i) v[q] += sigma2;
    if (j0 + 3 <= i) {
        float4 o; o.x = v[0]; o.y = v[1]; o.z = v[2]; o.w = v[3];
        *(float4*)(row + j0) = o;
    } else {
        #pragma unroll
        for (int q = 0; q < 4; ++q) if (j0 + q <= i) row[j0+q] = v[q];
    }
}

// ================= persistent cooperative Cholesky =================
// grid <= co-resident capacity; per panel: [sample-blocks: diag factor +
// TRSM + solve]  grid.sync  [all blocks: trailing SYRK]  grid.sync.
// bvec + quad/logdet live in sample-block LDS for the whole kernel.
__global__ __launch_bounds__(CGT, 4)
void coop_kernel(float* __restrict__ covb, const float* __restrict__ scal,
                 const float* __restrict__ y, float* __restrict__ out,
                 int mbase, int mc)
{
    __shared__ float bvec_s[NN];                       // persistent (sample-blocks)
    __shared__ float pq[2];                            // quad, logdet (persistent)
    __shared__ __align__(16) float smem[2 * 32 * 132]; // As/Bs; Tl/rs/sol overlay
    float* As = smem;
    float* Bs = smem + 32 * 132;
    float* Tl = smem;                // stride 68, 64 rows -> 4352 floats
    float* rs_s  = smem + 4352;
    float* sol_s = smem + 4416;

    cg::grid_group grid = cg::this_grid();
    int tid = threadIdx.x;
    int bid = blockIdx.x;
    bool is_sb = (bid < mc);
    float* Csb = covb + (size_t)bid * NN * NN;

    if (is_sb) {
        float beta = scal[4*NSAMP + (mbase + bid)];
        for (int r = tid; r < NN; r += CGT) bvec_s[r] = y[r] - beta;
        if (tid == 0) { pq[0] = 0.f; pq[1] = 0.f; }
        __syncthreads();
    }

    for (int p = 0; p < NN; p += NB) {
        // ---------- stage 1: diag factor + TRSM + forward solve ----------
        if (is_sb) {
            if (tid < 64) {
                int r = tid;
                float row[NB];
                const float* src = Csb + (size_t)(p + r) * NN + p;
                #pragma unroll
                for (int q = 0; q < NB/4; ++q) {
                    float4 v = *(const float4*)(src + 4*q);
                    row[4*q+0] = v.x; row[4*q+1] = v.y; row[4*q+2] = v.z; row[4*q+3] = v.w;
                }
                float b = bvec_s[p + r];
                float quad_add = 0.f;
                #pragma unroll
                for (int j = 0; j < NB; ++j) {
                    float dj = fmaxf(bcastf(row[j], j), 1e-30f);
                    float rs = rsqrtf(dj);
                    row[j] *= rs;
                    float sj = bcastf(b, j) * rs;
                    quad_add = fmaf(sj, sj, quad_add);
                    b = fmaf(-row[j], sj, b);
                    if (r == j) { rs_s[j] = rs; sol_s[j] = sj; }
                    #pragma unroll
                    for (int c = j + 1; c < NB; ++c) {
                        float s = bcastf(row[j], c);
                        row[c] = fmaf(-row[j], s, row[c]);
                    }
                }
                #pragma unroll
                for (int q = 0; q < NB/4; ++q) {
                    float4 v; v.x = row[4*q]; v.y = row[4*q+1]; v.z = row[4*q+2]; v.w = row[4*q+3];
                    *(float4*)&Tl[r * 68 + 4*q] = v;
                }
                if (r == 0) pq[0] += quad_add;
            }
            __syncthreads();
            if (tid >= 64 && tid < 128) {   // logdet
                int lane = tid - 64;
                float lv = logf(rs_s[lane]);
                #pragma unroll
                for (int off = 32; off > 0; off >>= 1) lv += __shfl_down(lv, off);
                if (lane == 0) pq[1] -= 2.f * lv;
            }
            // panel TRSM + RHS update
            for (int r0 = p + NB + tid; r0 < NN; r0 += CGT) {
                float* rowp = Csb + (size_t)r0 * NN + p;
                float l[NB];
                #pragma unroll
                for (int q = 0; q < NB/4; ++q) {
                    float4 v = *(const float4*)(rowp + 4*q);
                    l[4*q] = v.x; l[4*q+1] = v.y; l[4*q+2] = v.z; l[4*q+3] = v.w;
                }
                #pragma unroll
                for (int j = 0; j < NB; ++j) {
                    float acc = l[j];
                    int c = 0;
                    #pragma unroll
                    for (; c + 4 <= j; c += 4) {
                        float4 t = *(const float4*)&Tl[j * 68 + c];
                        acc = fmaf(-l[c],   t.x, acc);
                        acc = fmaf(-l[c+1], t.y, acc);
                        acc = fmaf(-l[c+2], t.z, acc);
                        acc = fmaf(-l[c+3], t.w, acc);
                    }
                    #pragma unroll
                    for (; c < j; ++c) acc = fmaf(-l[c], Tl[j * 68 + c], acc);
                    l[j] = acc * rs_s[j];
                }
                #pragma unroll
                for (int q = 0; q < NB/4; ++q) {
                    float4 v; v.x = l[4*q]; v.y = l[4*q+1]; v.z = l[4*q+2]; v.w = l[4*q+3];
                    *(float4*)(rowp + 4*q) = v;
                }
                float bacc = 0.f;
                #pragma unroll
                for (int j = 0; j < NB; ++j) bacc = fmaf(l[j], sol_s[j], bacc);
                bvec_s[r0] -= bacc;
            }
            __threadfence();
            __syncthreads();
        }

        int Tr = NN - p - NB;
        if (Tr <= 0) break;
        grid.sync();

        // ---------- stage 2: trailing SYRK over (pair, sample) items ----------
        {
            int nt = (Tr + TT - 1) / TT;
            int npairs = nt * (nt + 1) / 2;
            int items = npairs * mc;
            int base = p + NB;
            int tx = tid & 31, ty = tid >> 5;
            int c0 = tx * 4, r0g = ty * 8;
            for (int w = bid; w < items; w += gridDim.x) {
                int ml = w % mc;
                int pair = w / mc;
                int ti = 0;
                while ((ti + 1) * (ti + 2) / 2 <= pair) ++ti;
                int tj = pair - ti * (ti + 1) / 2;
                int ibase = base + ti * TT, jbase = base + tj * TT;
                float* Cm = covb + (size_t)ml * NN * NN;

                float4 acc[8];
                #pragma unroll
                for (int r = 0; r < 8; ++r) acc[r] = make_float4(0,0,0,0);

                #pragma unroll
                for (int ks = 0; ks < NB; ks += 32) {
                    for (int idx = tid; idx < TT * 8; idx += CGT) {
                        int ii = idx >> 3;
                        int c4 = (idx & 7) << 2;
                        int gr = ibase + ii;
                        float4 v = make_float4(0,0,0,0);
                        if (gr < NN) v = *(const float4*)(Cm + (size_t)gr * NN + p + ks + c4);
                        As[(c4+0)*132 + ii] = v.x; As[(c4+1)*132 + ii] = v.y;
                        As[(c4+2)*132 + ii] = v.z; As[(c4+3)*132 + ii] = v.w;
                    }
                    if (ti != tj) {
                        for (int idx = tid; idx < TT * 8; idx += CGT) {
                            int ii = idx >> 3;
                            int c4 = (idx & 7) << 2;
                            int gr = jbase + ii;
                            float4 v = make_float4(0,0,0,0);
                            if (gr < NN) v = *(const float4*)(Cm + (size_t)gr * NN + p + ks + c4);
                            Bs[(c4+0)*132 + ii] = v.x; Bs[(c4+1)*132 + ii] = v.y;
                            Bs[(c4+2)*132 + ii] = v.z; Bs[(c4+3)*132 + ii] = v.w;
                        }
                    }
                    __syncthreads();
                    const float* Bp = (ti == tj) ? As : Bs;
                    #pragma unroll
                    for (int k = 0; k < 32; ++k) {
                        float4 bv = *(const float4*)&Bp[k*132 + c0];
                        float4 a0 = *(const float4*)&As[k*132 + r0g];
                        float4 a1 = *(const float4*)&As[k*132 + r0g + 4];
                        float ar[8] = {a0.x, a0.y, a0.z, a0.w, a1.x, a1.y, a1.z, a1.w};
                        #pragma unroll
                        for (int r = 0; r < 8; ++r) fma4(acc[r], ar[r], bv);
                    }
                    __syncthreads();
                }

                int jcol = jbase + c0;
                #pragma unroll
                for (int r = 0; r < 8; ++r) {
                    int g = ibase + r0g + r;
                    if (g < NN && jcol < NN) {
                        float* cp = Cm + (size_t)g * NN + jcol;
                        if (jcol + 3 < NN) {
                            float4 u = *(float4*)cp;
                            u.x -= acc[r].x; u.y -= acc[r].y; u.z -= acc[r].z; u.w -= acc[r].w;
                            *(float4*)cp = u;
                        } else {
                            float av[4] = {acc[r].x, acc[r].y, acc[r].z, acc[r].w};
                            for (int q = 0; q < 4; ++q)
                                if (jcol + q < NN) cp[q] -= av[q];
                        }
                    }
                }
            }
            __threadfence();
        }
        grid.sync();
    }

    if (is_sb && tid == 0)
        out[mbase + bid] = -0.5f * (pq[0] + pq[1] + (float)NN * LOG2PI)
                         + scal[5*NSAMP + (mbase + bid)];
}

// ================= fallback (round-2 path) =================
__global__ __launch_bounds__(512)
void fact_kernel(float* __restrict__ covb, float* __restrict__ bvec,
                 float* __restrict__ stats, const float* __restrict__ scal,
                 float* __restrict__ out, int mbase, int p)
{
    int ml = blockIdx.x, m = mbase + ml;
    float* C = covb + (size_t)ml * NN * NN;
    __shared__ __align__(16) float Tl[NB][68];
    __shared__ float rs_s[NB], sol_s[NB], s_quad;
    int tid = threadIdx.x;

    if (tid < 64) {
        int r = tid;
        float row[NB];
        const float* src = C + (size_t)(p + r) * NN + p;
        #pragma unroll
        for (int q = 0; q < NB/4; ++q) {
            float4 v = *(const float4*)(src + 4*q);
            row[4*q+0] = v.x; row[4*q+1] = v.y; row[4*q+2] = v.z; row[4*q+3] = v.w;
        }
        float b = bvec[(size_t)m * NN + p + r];
        float quad_add = 0.f;
        #pragma unroll
        for (int j = 0; j < NB; ++j) {
            float dj = fmaxf(bcastf(row[j], j), 1e-30f);
            float rs = rsqrtf(dj);
            row[j] *= rs;
            float sj = bcastf(b, j) * rs;
            quad_add = fmaf(sj, sj, quad_add);
            b = fmaf(-row[j], sj, b);
            if (r == j) { rs_s[j] = rs; sol_s[j] = sj; }
            #pragma unroll
            for (int c = j + 1; c < NB; ++c) {
                float s = bcastf(row[j], c);
                row[c] = fmaf(-row[j], s, row[c]);
            }
        }
        #pragma unroll
        for (int q = 0; q < NB/4; ++q) {
            float4 v; v.x = row[4*q]; v.y = row[4*q+1]; v.z = row[4*q+2]; v.w = row[4*q+3];
            *(float4*)&Tl[r][4*q] = v;
        }
        if (r == 0) s_quad = quad_add;
    }
    __syncthreads();

    if (tid >= 64 && tid < 128) {
        float lv = logf(rs_s[tid - 64]);
        #pragma unroll
        for (int off = 32; off > 0; off >>= 1) lv += __shfl_down(lv, off);
        if (tid == 64) {
            float qt = stats[2*m] + s_quad;
            float lt = stats[2*m+1] - 2.f * lv;
            stats[2*m] = qt; stats[2*m+1] = lt;
            if (p == NN - NB)
                out[m] = -0.5f * (qt + lt + (float)NN * LOG2PI) + scal[5*NSAMP + m];
        }
    }

    for (int r0 = p + NB + tid; r0 < NN; r0 += 512) {
        float* rowp = C + (size_t)r0 * NN + p;
        float l[NB];
        #pragma unroll
        for (int q = 0; q < NB/4; ++q) {
            float4 v = *(const float4*)(rowp + 4*q);
            l[4*q] = v.x; l[4*q+1] = v.y; l[4*q+2] = v.z; l[4*q+3] = v.w;
        }
        #pragma unroll
        for (int j = 0; j < NB; ++j) {
            float acc = l[j];
            #pragma unroll
            for (int c = 0; c < j; ++c) acc = fmaf(-l[c], Tl[j][c], acc);
            l[j] = acc * rs_s[j];
        }
        #pragma unroll
        for (int q = 0; q < NB/4; ++q) {
            float4 v; v.x = l[4*q]; v.y = l[4*q+1]; v.z = l[4*q+2]; v.w = l[4*q+3];
            *(float4*)(rowp + 4*q) = v;
        }
        float bacc = 0.f;
        #pragma unroll
        for (int j = 0; j < NB; ++j) bacc = fmaf(l[j], sol_s[j], bacc);
        bvec[(size_t)m * NN + r0] -= bacc;
    }
}

__global__ __launch_bounds__(256)
void syrk_kernel(float* __restrict__ covb, int p)
{
    int ml = blockIdx.y;
    float* C = covb + (size_t)ml * NN * NN;
    int pair = blockIdx.x;
    int ti = 0;
    while ((ti + 1) * (ti + 2) / 2 <= pair) ++ti;
    int tj = pair - ti * (ti + 1) / 2;
    int base = p + NB;
    int ibase = base + ti * TT, jbase = base + tj * TT;

    __shared__ __align__(16) float As[32][TT+4];
    __shared__ __align__(16) float Bs[32][TT+4];
    int tid = threadIdx.x;
    int tx = tid & 15, ty = tid >> 4;
    int c0 = tx * 8, r0g = ty * 8;

    float4 acc[8][2];
    #pragma unroll
    for (int r = 0; r < 8; ++r) { acc[r][0] = make_float4(0,0,0,0); acc[r][1] = make_float4(0,0,0,0); }

    #pragma unroll
    for (int ks = 0; ks < NB; ks += 32) {
        for (int idx = tid; idx < TT * 8; idx += 256) {
            int ii = idx >> 3;
            int c4 = (idx & 7) << 2;
            int gr = ibase + ii;
            float4 v = make_float4(0,0,0,0);
            if (gr < NN) v = *(const float4*)(C + (size_t)gr * NN + p + ks + c4);
            As[c4][ii] = v.x; As[c4+1][ii] = v.y; As[c4+2][ii] = v.z; As[c4+3][ii] = v.w;
        }
        if (ti != tj) {
            for (int idx = tid; idx < TT * 8; idx += 256) {
                int ii = idx >> 3;
                int c4 = (idx & 7) << 2;
                int gr = jbase + ii;
                float4 v = make_float4(0,0,0,0);
                if (gr < NN) v = *(const float4*)(C + (size_t)gr * NN + p + ks + c4);
                Bs[c4][ii] = v.x; Bs[c4+1][ii] = v.y; Bs[c4+2][ii] = v.z; Bs[c4+3][ii] = v.w;
            }
        }
        __syncthreads();
        const float (*Bp)[TT+4] = (ti == tj) ? As : Bs;
        #pragma unroll
        for (int k = 0; k < 32; ++k) {
            float4 b0 = *(const float4*)&Bp[k][c0];
            float4 b1 = *(const float4*)&Bp[k][c0 + 4];
            float4 a0 = *(const float4*)&As[k][r0g];
            float4 a1 = *(const float4*)&As[k][r0g + 4];
            float ar[8] = {a0.x, a0.y, a0.z, a0.w, a1.x, a1.y, a1.z, a1.w};
            #pragma unroll
            for (int r = 0; r < 8; ++r) {
                fma4(acc[r][0], ar[r], b0);
                fma4(acc[r][1], ar[r], b1);
            }
        }
        __syncthreads();
    }

    int jcol = jbase + c0;
    #pragma unroll
    for (int r = 0; r < 8; ++r) {
        int g = ibase + r0g + r;
        if (g < NN) {
            float* cp = C + (size_t)g * NN + jcol;
            if (jcol + 7 < NN) {
                float4 u0 = *(float4*)cp;
                float4 u1 = *((float4*)cp + 1);
                u0.x -= acc[r][0].x; u0.y -= acc[r][0].y; u0.z -= acc[r][0].z; u0.w -= acc[r][0].w;
                u1.x -= acc[r][1].x; u1.y -= acc[r][1].y; u1.z -= acc[r][1].z; u1.w -= acc[r][1].w;
                *(float4*)cp = u0;
                *((float4*)cp + 1) = u1;
            } else {
                float av[8] = {acc[r][0].x, acc[r][0].y, acc[r][0].z, acc[r][0].w,
                               acc[r][1].x, acc[r][1].y, acc[r][1].z, acc[r][1].w};
                #pragma unroll
                for (int q = 0; q < 8; ++q)
                    if (jcol + q < NN) cp[q] -= av[q];
            }
        }
    }
}

extern "C" void kernel_launch(void* const* d_in, const int* in_sizes, int n_in,
                              void* d_out, int out_size, void* d_ws, size_t ws_size,
                              hipStream_t stream)
{
    const float* x   = (const float*)d_in[0];
    const float* y   = (const float*)d_in[1];
    const float* z   = (const float*)d_in[2];
    const float* qbm = (const float*)d_in[3];
    const float* qbs = (const float*)d_in[4];
    const float* qsm = (const float*)d_in[5];
    const float* qss = (const float*)d_in[6];
    const float* qem = (const float*)d_in[7];
    const float* qes = (const float*)d_in[8];
    const float* qzm = (const float*)d_in[9];
    const float* qzs = (const float*)d_in[10];
    const float* qnm = (const float*)d_in[11];
    const float* qns = (const float*)d_in[12];
    float* out  = (float*)d_out;
    float* ws   = (float*)d_ws;

    float* scal  = ws;                       // 384 used, 1024 reserved
    float* bvec  = ws + 1024;                // fallback path only
    float* stats = ws + 1024 + NSAMP*NN;     // fallback path only
    float* cov   = ws + 1024 + NSAMP*NN + 512;
    size_t headF = 1024 + (size_t)NSAMP*NN + 512;

    scal_kernel<<<1, 64, 0, stream>>>(z, qbm, qbs, qsm, qss, qem, qes, qzm, qzs, qnm, qns, scal);

    size_t availF = ws_size / 4;
    size_t perM   = (size_t)NN * NN;
    int mc_max = NSAMP;
    if (availF < headF + (size_t)NSAMP * perM) {
        size_t rem = (availF > headF) ? (availF - headF) : 0;
        mc_max = (int)(rem / perM);
        if (mc_max < 1) mc_max = 1;
        if (mc_max > NSAMP) mc_max = NSAMP;
    }

    int occ = 0;
    hipError_t oerr = hipOccupancyMaxActiveBlocksPerMultiprocessor(&occ, (const void*)coop_kernel, CGT, 0);
    if (oerr != hipSuccess || occ < 1) occ = 1;
    int grid = occ * 256;
    if (grid > 512) grid = 512;

    for (int mb = 0; mb < NSAMP; mb += mc_max) {
        int mc = NSAMP - mb; if (mc > mc_max) mc = mc_max;
        cov_kernel<<<dim3(NN, mc), 256, 0, stream>>>(cov, scal, x, y, bvec, stats, mb);

        int mbase_a = mb, mc_a = mc;
        void* args[] = { (void*)&cov, (void*)&scal, (void*)&y, (void*)&out,
                         (void*)&mbase_a, (void*)&mc_a };
        hipError_t cerr = hipLaunchCooperativeKernel((const void*)coop_kernel,
                              dim3(grid), dim3(CGT), args, 0, stream);
        if (cerr != hipSuccess) {
            // fallback: multi-launch right-looking path
            for (int p = 0; p < NN; p += NB) {
                fact_kernel<<<mc, 512, 0, stream>>>(cov, bvec, stats, scal, out, mb, p);
                int Tr = NN - p - NB;
                if (Tr > 0) {
                    int nt = (Tr + TT - 1) / TT;
                    int npairs = nt * (nt + 1) / 2;
                    syrk_kernel<<<dim3(npairs, mc), 256, 0, stream>>>(cov, p);
                }
            }
        }
    }
}

// Round 4
// 8330.693 us; speedup vs baseline: 2.4217x; 2.4217x over previous
//
#include <hip/hip_runtime.h>
#include <math.h>

#define NN 1024      // N
#define NB 64        // panel width
#define TT 128       // trailing SYRK tile
#define NSAMP 64     // n_mc

#define CCONST  (-0.91893853320467274f)   // -0.5*log(2*pi)
#define LOG2PI  (1.8378770664093453f)

__device__ __forceinline__ float bcastf(float v, int lane) {
    return __int_as_float(__builtin_amdgcn_readlane(__float_as_int(v), lane));
}
__device__ __forceinline__ float softplus_d(float v) {
    return (v > 20.f ? v : log1pf(expf(v))) + 1e-7f;
}
__device__ __forceinline__ float log_normal_f(float v, float mean, float s, float eps) {
    float d = v - mean;
    return -d * d / (2.f * s * s + eps) - logf(s) + CCONST;
}
__device__ __forceinline__ float log_lognormal_f(float v, float mean, float s) {
    float lv = logf(v);
    float d = lv - mean;
    return -d * d / (2.f * s * s + 1e-6f) - lv - logf(s) + CCONST;
}
__device__ __forceinline__ void fma4(float4& c, float a, const float4& b) {
    c.x = fmaf(a, b.x, c.x); c.y = fmaf(a, b.y, c.y);
    c.z = fmaf(a, b.z, c.z); c.w = fmaf(a, b.w, c.w);
}

// ---------------- per-sample scalars ----------------
__global__ void scal_kernel(const float* __restrict__ z,
    const float* qbm, const float* qbs, const float* qsm, const float* qss,
    const float* qem, const float* qes, const float* qzm, const float* qzs,
    const float* qnm, const float* qns, float* __restrict__ scal)
{
    int m = threadIdx.x;
    if (m >= NSAMP) return;
    float z0 = z[m*5+0], z1 = z[m*5+1], z2 = z[m*5+2], z3 = z[m*5+3], z4 = z[m*5+4];
    float spb = softplus_d(qbs[0]);
    float sps = softplus_d(qss[0]);
    float spe = softplus_d(qes[0]);
    float spz = softplus_d(qzs[0]);
    float spn = softplus_d(qns[0]);
    float sigma2 = expf(z0 * sps + qsm[0]);
    float beta   = z1 * spb + qbm[0];
    float eta    = expf(z2 * spe + qem[0]);
    float lsZ    = expf(z3 * spz + qzm[0]);
    float lsN    = expf(z4 * spn + qnm[0]);
    float s0 = softplus_d(sqrtf(logf(2.f)));
    float lp = log_normal_f(beta, 0.f, 1.f, 1e-5f)
             + log_lognormal_f(sigma2, 1.f, s0)
             + log_lognormal_f(eta,    1.f, s0)
             + log_lognormal_f(lsZ,    1.f, s0)
             + log_lognormal_f(lsN,    1.f, s0);
    float lq = log_normal_f(beta, qbm[0], spb, 1e-5f)
             + log_lognormal_f(sigma2, qsm[0], sps)
             + log_lognormal_f(eta,    qem[0], spe)
             + log_lognormal_f(lsZ,    qzm[0], spz)
             + log_lognormal_f(lsN,    qnm[0], spn);
    scal[m]           = sigma2;
    scal[NSAMP + m]   = eta;
    scal[2*NSAMP + m] = 1.f / lsZ;
    scal[3*NSAMP + m] = 1.f / lsN;
    scal[4*NSAMP + m] = beta;
    scal[5*NSAMP + m] = lp - lq;
}

// ---------------- covariance build (lower triangle) + bvec/stats init ----------------
__global__ __launch_bounds__(256)
void cov_kernel(float* __restrict__ cov, const float* __restrict__ scal,
                const float* __restrict__ x, const float* __restrict__ y,
                float* __restrict__ bvec, float* __restrict__ stats, int mbase)
{
    int i  = blockIdx.x;
    int ml = blockIdx.y;
    int m  = mbase + ml;
    if (threadIdx.x == 0) {
        bvec[(size_t)m * NN + i] = y[i] - scal[4*NSAMP + m];
        if (i == 0) { stats[2*m] = 0.f; stats[2*m+1] = 0.f; }
    }
    float sigma2 = scal[m];
    float eta    = scal[NSAMP + m];
    float ilZ    = scal[2*NSAMP + m];
    float ilN    = scal[3*NSAMP + m];
    float xi0 = x[2*i]   * ilZ;
    float xi1 = x[2*i+1] * ilN;
    float* row = cov + (size_t)ml * NN * NN + (size_t)i * NN;
    int j0 = threadIdx.x * 4;
    if (j0 > i) return;
    float4 xa = *(const float4*)(x + 2*j0);
    float4 xb = *(const float4*)(x + 2*j0 + 4);
    float v[4]; float d0, d1;
    d0 = xa.x*ilZ - xi0; d1 = xa.y*ilN - xi1; v[0] = eta*__expf(-0.5f*(d0*d0+d1*d1));
    d0 = xa.z*ilZ - xi0; d1 = xa.w*ilN - xi1; v[1] = eta*__expf(-0.5f*(d0*d0+d1*d1));
    d0 = xb.x*ilZ - xi0; d1 = xb.y*ilN - xi1; v[2] = eta*__expf(-0.5f*(d0*d0+d1*d1));
    d0 = xb.z*ilZ - xi0; d1 = xb.w*ilN - xi1; v[3] = eta*__expf(-0.5f*(d0*d0+d1*d1));
    #pragma unroll
    for (int q = 0; q < 4; ++q) if (j0 + q == i) v[q] += sigma2;
    if (j0 + 3 <= i) {
        float4 o; o.x = v[0]; o.y = v[1]; o.z = v[2]; o.w = v[3];
        *(float4*)(row + j0) = o;
    } else {
        #pragma unroll
        for (int q = 0; q < 4; ++q) if (j0 + q <= i) row[j0+q] = v[q];
    }
}

// ---------------- wave-register 64x64 diagonal factor + fused solve ----------------
// executed by threads 0..63 (one wave); lane r owns row r of the block.
__device__ __forceinline__ void diag_factor(float* __restrict__ C,
    float* __restrict__ bvec, float* __restrict__ rs_ws, float* __restrict__ sol_ws,
    float* __restrict__ stats, float* __restrict__ out, const float* __restrict__ scal,
    int m, int p, int r)
{
    float row[NB];
    float* src = C + (size_t)(p + r) * NN + p;
    #pragma unroll
    for (int q = 0; q < NB/4; ++q) {
        float4 v = *(const float4*)(src + 4*q);
        row[4*q+0] = v.x; row[4*q+1] = v.y; row[4*q+2] = v.z; row[4*q+3] = v.w;
    }
    float b = bvec[(size_t)m * NN + p + r];
    float quad_add = 0.f, my_d = 1.f;
    #pragma unroll
    for (int j = 0; j < NB; ++j) {
        float dj = fmaxf(bcastf(row[j], j), 1e-30f);
        float rs = rsqrtf(dj);
        if (r == j) my_d = dj;
        row[j] *= rs;                       // row[j] = L[r][j] for r>=j
        float sj = bcastf(b, j) * rs;
        quad_add = fmaf(sj, sj, quad_add);
        b = fmaf(-row[j], sj, b);
        if (r == j) { rs_ws[m*NB + j] = rs; sol_ws[m*NB + j] = sj; }
        #pragma unroll
        for (int c = j + 1; c < NB; ++c) {
            float s = bcastf(row[j], c);    // = L[c][j]
            row[c] = fmaf(-row[j], s, row[c]);
        }
    }
    #pragma unroll
    for (int q = 0; q < NB/4; ++q) {
        float4 v; v.x = row[4*q]; v.y = row[4*q+1]; v.z = row[4*q+2]; v.w = row[4*q+3];
        *(float4*)(src + 4*q) = v;
    }
    float ldv = logf(my_d);
    #pragma unroll
    for (int off = 32; off > 0; off >>= 1) ldv += __shfl_down(ldv, off);
    if (r == 0) {
        float qt = stats[2*m]   + quad_add;
        float lt = stats[2*m+1] + ldv;
        stats[2*m] = qt; stats[2*m+1] = lt;
        if (p == NN - NB)
            out[m] = -0.5f * (qt + lt + (float)NN * LOG2PI) + scal[5*NSAMP + m];
    }
}

__global__ __launch_bounds__(64)
void diag_kernel(float* __restrict__ covb, float* __restrict__ bvec,
                 float* __restrict__ rs_ws, float* __restrict__ sol_ws,
                 float* __restrict__ stats, float* __restrict__ out,
                 const float* __restrict__ scal, int mbase, int p)
{
    int ml = blockIdx.x;
    float* C = covb + (size_t)ml * NN * NN;
    diag_factor(C, bvec, rs_ws, sol_ws, stats, out, scal, mbase + ml, p, threadIdx.x);
}

// ---------------- panel TRSM (parallel across row-tiles and samples) ----------------
// grid (row-tiles, mc); 256 threads, one row per thread. L11/rs/sol staged in LDS;
// inner-loop LDS reads are wave-uniform (broadcast, conflict-free).
__global__ __launch_bounds__(256)
void trsm_kernel(float* __restrict__ covb, float* __restrict__ bvec,
                 const float* __restrict__ rs_ws, const float* __restrict__ sol_ws,
                 int mbase, int p)
{
    int ml = blockIdx.y;
    int m  = mbase + ml;
    float* C = covb + (size_t)ml * NN * NN;
    __shared__ __align__(16) float Tl[NB][68];
    __shared__ float rs_s[NB], sol_s[NB];
    int tid = threadIdx.x;

    for (int idx = tid; idx < NB * (NB/4); idx += 256) {
        int rr = idx >> 4, c4 = (idx & 15) << 2;
        *(float4*)&Tl[rr][c4] = *(const float4*)(C + (size_t)(p + rr) * NN + p + c4);
    }
    if (tid < NB) { rs_s[tid] = rs_ws[m*NB + tid]; sol_s[tid] = sol_ws[m*NB + tid]; }
    __syncthreads();

    int r0 = p + NB + blockIdx.x * 256 + tid;
    if (r0 >= NN) return;
    float* rowp = C + (size_t)r0 * NN + p;
    float l[NB];
    #pragma unroll
    for (int q = 0; q < NB/4; ++q) {
        float4 v = *(const float4*)(rowp + 4*q);
        l[4*q] = v.x; l[4*q+1] = v.y; l[4*q+2] = v.z; l[4*q+3] = v.w;
    }
    #pragma unroll
    for (int j = 0; j < NB; ++j) {
        float acc = l[j];
        int c = 0;
        #pragma unroll
        for (; c + 4 <= j; c += 4) {
            float4 t = *(const float4*)&Tl[j][c];
            acc = fmaf(-l[c],   t.x, acc);
            acc = fmaf(-l[c+1], t.y, acc);
            acc = fmaf(-l[c+2], t.z, acc);
            acc = fmaf(-l[c+3], t.w, acc);
        }
        #pragma unroll
        for (; c < j; ++c) acc = fmaf(-l[c], Tl[j][c], acc);
        l[j] = acc * rs_s[j];
    }
    #pragma unroll
    for (int q = 0; q < NB/4; ++q) {
        float4 v; v.x = l[4*q]; v.y = l[4*q+1]; v.z = l[4*q+2]; v.w = l[4*q+3];
        *(float4*)(rowp + 4*q) = v;
    }
    float bacc = 0.f;
    #pragma unroll
    for (int j = 0; j < NB; ++j) bacc = fmaf(l[j], sol_s[j], bacc);
    bvec[(size_t)m * NN + r0] -= bacc;
}

// ---------------- trailing SYRK: C[i,j] -= sum_k L[i,k] L[j,k] ----------------
// grid (pairs, samples); 512 threads; 128x128 tile; 8 rows x 4 cols per thread
// (round-3 stage-2 shape: VGPR ~64 -> 4 blocks/CU with 33.9 KB LDS).
__global__ __launch_bounds__(512)
void syrk_kernel(float* __restrict__ covb, int p)
{
    int ml = blockIdx.y;
    float* C = covb + (size_t)ml * NN * NN;
    int pair = blockIdx.x;
    int ti = 0;
    while ((ti + 1) * (ti + 2) / 2 <= pair) ++ti;
    int tj = pair - ti * (ti + 1) / 2;
    int base = p + NB;
    int ibase = base + ti * TT, jbase = base + tj * TT;

    __shared__ __align__(16) float As[32][TT+4];
    __shared__ __align__(16) float Bs[32][TT+4];
    int tid = threadIdx.x;
    int tx = tid & 31, ty = tid >> 5;
    int c0 = tx * 4, r0g = ty * 8;

    float4 acc[8];
    #pragma unroll
    for (int r = 0; r < 8; ++r) acc[r] = make_float4(0,0,0,0);

    #pragma unroll
    for (int ks = 0; ks < NB; ks += 32) {
        for (int idx = tid; idx < TT * 8; idx += 512) {
            int ii = idx >> 3;
            int c4 = (idx & 7) << 2;
            int gr = ibase + ii;
            float4 v = make_float4(0,0,0,0);
            if (gr < NN) v = *(const float4*)(C + (size_t)gr * NN + p + ks + c4);
            As[c4+0][ii] = v.x; As[c4+1][ii] = v.y;
            As[c4+2][ii] = v.z; As[c4+3][ii] = v.w;
        }
        if (ti != tj) {
            for (int idx = tid; idx < TT * 8; idx += 512) {
                int ii = idx >> 3;
                int c4 = (idx & 7) << 2;
                int gr = jbase + ii;
                float4 v = make_float4(0,0,0,0);
                if (gr < NN) v = *(const float4*)(C + (size_t)gr * NN + p + ks + c4);
                Bs[c4+0][ii] = v.x; Bs[c4+1][ii] = v.y;
                Bs[c4+2][ii] = v.z; Bs[c4+3][ii] = v.w;
            }
        }
        __syncthreads();
        const float (*Bp)[TT+4] = (ti == tj) ? As : Bs;
        #pragma unroll
        for (int k = 0; k < 32; ++k) {
            float4 bv = *(const float4*)&Bp[k][c0];
            float4 a0 = *(const float4*)&As[k][r0g];
            float4 a1 = *(const float4*)&As[k][r0g + 4];
            float ar[8] = {a0.x, a0.y, a0.z, a0.w, a1.x, a1.y, a1.z, a1.w};
            #pragma unroll
            for (int r = 0; r < 8; ++r) fma4(acc[r], ar[r], bv);
        }
        __syncthreads();
    }

    int jcol = jbase + c0;
    if (jcol >= NN) return;
    #pragma unroll
    for (int r = 0; r < 8; ++r) {
        int g = ibase + r0g + r;
        if (g < NN) {
            float* cp = C + (size_t)g * NN + jcol;
            float4 u = *(float4*)cp;
            u.x -= acc[r].x; u.y -= acc[r].y; u.z -= acc[r].z; u.w -= acc[r].w;
            *(float4*)cp = u;
        }
    }
}

extern "C" void kernel_launch(void* const* d_in, const int* in_sizes, int n_in,
                              void* d_out, int out_size, void* d_ws, size_t ws_size,
                              hipStream_t stream)
{
    const float* x   = (const float*)d_in[0];
    const float* y   = (const float*)d_in[1];
    const float* z   = (const float*)d_in[2];
    const float* qbm = (const float*)d_in[3];
    const float* qbs = (const float*)d_in[4];
    const float* qsm = (const float*)d_in[5];
    const float* qss = (const float*)d_in[6];
    const float* qem = (const float*)d_in[7];
    const float* qes = (const float*)d_in[8];
    const float* qzm = (const float*)d_in[9];
    const float* qzs = (const float*)d_in[10];
    const float* qnm = (const float*)d_in[11];
    const float* qns = (const float*)d_in[12];
    float* out  = (float*)d_out;
    float* ws   = (float*)d_ws;

    // workspace layout (floats)
    float* scal   = ws;                                   // 384 used
    float* bvec   = ws + 1024;                            // 64*1024
    float* stats  = ws + 1024 + NSAMP*NN;                 // 128 used, 512 res
    float* rs_ws  = ws + 1024 + NSAMP*NN + 512;           // 64*64
    float* sol_ws = ws + 1024 + NSAMP*NN + 512 + NSAMP*NB;
    float* cov    = ws + 1024 + NSAMP*NN + 512 + 2*NSAMP*NB;
    size_t headF  = 1024 + (size_t)NSAMP*NN + 512 + 2*(size_t)NSAMP*NB;

    scal_kernel<<<1, 64, 0, stream>>>(z, qbm, qbs, qsm, qss, qem, qes, qzm, qzs, qnm, qns, scal);

    size_t availF = ws_size / 4;
    size_t perM   = (size_t)NN * NN;
    int mc_max = NSAMP;
    if (availF < headF + (size_t)NSAMP * perM) {
        size_t rem = (availF > headF) ? (availF - headF) : 0;
        mc_max = (int)(rem / perM);
        if (mc_max < 1) mc_max = 1;
        if (mc_max > NSAMP) mc_max = NSAMP;
    }

    for (int mb = 0; mb < NSAMP; mb += mc_max) {
        int mc = NSAMP - mb; if (mc > mc_max) mc = mc_max;
        cov_kernel<<<dim3(NN, mc), 256, 0, stream>>>(cov, scal, x, y, bvec, stats, mb);
        for (int p = 0; p < NN; p += NB) {
            diag_kernel<<<mc, 64, 0, stream>>>(cov, bvec, rs_ws, sol_ws, stats, out, scal, mb, p);
            int rb = NN - p - NB;              // rows below the diag block
            if (rb > 0) {
                int rtiles = (rb + 255) / 256;
                trsm_kernel<<<dim3(rtiles, mc), 256, 0, stream>>>(cov, bvec, rs_ws, sol_ws, mb, p);
                int nt = (rb + TT - 1) / TT;
                int npairs = nt * (nt + 1) / 2;
                syrk_kernel<<<dim3(npairs, mc), 512, 0, stream>>>(cov, p);
            }
        }
    }
}

// Round 5
// 3476.069 us; speedup vs baseline: 5.8037x; 2.3966x over previous
//
#include <hip/hip_runtime.h>
#include <math.h>

#define NN 1024      // N
#define NB 64        // panel width
#define NSAMP 64     // n_mc

#define CCONST  (-0.91893853320467274f)   // -0.5*log(2*pi)
#define LOG2PI  (1.8378770664093453f)

__device__ __forceinline__ float bcastf(float v, int lane) {
    return __int_as_float(__builtin_amdgcn_readlane(__float_as_int(v), lane));
}
__device__ __forceinline__ float softplus_d(float v) {
    return (v > 20.f ? v : log1pf(expf(v))) + 1e-7f;
}
__device__ __forceinline__ float log_normal_f(float v, float mean, float s, float eps) {
    float d = v - mean;
    return -d * d / (2.f * s * s + eps) - logf(s) + CCONST;
}
__device__ __forceinline__ float log_lognormal_f(float v, float mean, float s) {
    float lv = logf(v);
    float d = lv - mean;
    return -d * d / (2.f * s * s + 1e-6f) - lv - logf(s) + CCONST;
}
__device__ __forceinline__ void fma4(float4& c, float a, const float4& b) {
    c.x = fmaf(a, b.x, c.x); c.y = fmaf(a, b.y, c.y);
    c.z = fmaf(a, b.z, c.z); c.w = fmaf(a, b.w, c.w);
}

// ---------------- per-sample scalars ----------------
__global__ void scal_kernel(const float* __restrict__ z,
    const float* qbm, const float* qbs, const float* qsm, const float* qss,
    const float* qem, const float* qes, const float* qzm, const float* qzs,
    const float* qnm, const float* qns, float* __restrict__ scal)
{
    int m = threadIdx.x;
    if (m >= NSAMP) return;
    float z0 = z[m*5+0], z1 = z[m*5+1], z2 = z[m*5+2], z3 = z[m*5+3], z4 = z[m*5+4];
    float spb = softplus_d(qbs[0]);
    float sps = softplus_d(qss[0]);
    float spe = softplus_d(qes[0]);
    float spz = softplus_d(qzs[0]);
    float spn = softplus_d(qns[0]);
    float sigma2 = expf(z0 * sps + qsm[0]);
    float beta   = z1 * spb + qbm[0];
    float eta    = expf(z2 * spe + qem[0]);
    float lsZ    = expf(z3 * spz + qzm[0]);
    float lsN    = expf(z4 * spn + qnm[0]);
    float s0 = softplus_d(sqrtf(logf(2.f)));
    float lp = log_normal_f(beta, 0.f, 1.f, 1e-5f)
             + log_lognormal_f(sigma2, 1.f, s0)
             + log_lognormal_f(eta,    1.f, s0)
             + log_lognormal_f(lsZ,    1.f, s0)
             + log_lognormal_f(lsN,    1.f, s0);
    float lq = log_normal_f(beta, qbm[0], spb, 1e-5f)
             + log_lognormal_f(sigma2, qsm[0], sps)
             + log_lognormal_f(eta,    qem[0], spe)
             + log_lognormal_f(lsZ,    qzm[0], spz)
             + log_lognormal_f(lsN,    qnm[0], spn);
    scal[m]           = sigma2;
    scal[NSAMP + m]   = eta;
    scal[2*NSAMP + m] = 1.f / lsZ;
    scal[3*NSAMP + m] = 1.f / lsN;
    scal[4*NSAMP + m] = beta;
    scal[5*NSAMP + m] = lp - lq;
}

// ---------------- covariance build (lower triangle) + bvec/stats init ----------------
__global__ __launch_bounds__(256)
void cov_kernel(float* __restrict__ cov, const float* __restrict__ scal,
                const float* __restrict__ x, const float* __restrict__ y,
                float* __restrict__ bvec, float* __restrict__ stats, int mbase)
{
    int i  = blockIdx.x;
    int ml = blockIdx.y;
    int m  = mbase + ml;
    if (threadIdx.x == 0) {
        bvec[(size_t)m * NN + i] = y[i] - scal[4*NSAMP + m];
        if (i == 0) { stats[2*m] = 0.f; stats[2*m+1] = 0.f; }
    }
    float sigma2 = scal[m];
    float eta    = scal[NSAMP + m];
    float ilZ    = scal[2*NSAMP + m];
    float ilN    = scal[3*NSAMP + m];
    float xi0 = x[2*i]   * ilZ;
    float xi1 = x[2*i+1] * ilN;
    float* row = cov + (size_t)ml * NN * NN + (size_t)i * NN;
    int j0 = threadIdx.x * 4;
    if (j0 > i) return;
    float4 xa = *(const float4*)(x + 2*j0);
    float4 xb = *(const float4*)(x + 2*j0 + 4);
    float v[4]; float d0, d1;
    d0 = xa.x*ilZ - xi0; d1 = xa.y*ilN - xi1; v[0] = eta*__expf(-0.5f*(d0*d0+d1*d1));
    d0 = xa.z*ilZ - xi0; d1 = xa.w*ilN - xi1; v[1] = eta*__expf(-0.5f*(d0*d0+d1*d1));
    d0 = xb.x*ilZ - xi0; d1 = xb.y*ilN - xi1; v[2] = eta*__expf(-0.5f*(d0*d0+d1*d1));
    d0 = xb.z*ilZ - xi0; d1 = xb.w*ilN - xi1; v[3] = eta*__expf(-0.5f*(d0*d0+d1*d1));
    #pragma unroll
    for (int q = 0; q < 4; ++q) if (j0 + q == i) v[q] += sigma2;
    if (j0 + 3 <= i) {
        float4 o; o.x = v[0]; o.y = v[1]; o.z = v[2]; o.w = v[3];
        *(float4*)(row + j0) = o;
    } else {
        #pragma unroll
        for (int q = 0; q < 4; ++q) if (j0 + q <= i) row[j0+q] = v[q];
    }
}

// ---------------- left-looking block-column update (GEMM, K = p) ----------------
// C[r, p:p+64] -= sum_{k<p} L[r,k] * L[p+c,k]   for r in [p + bx*128, ...)
// 256 threads; output tile 128 rows x 64 cols; 4 rows x 8 cols per thread.
__global__ __launch_bounds__(256)
void update_kernel(float* __restrict__ covb, int p)
{
    int ml = blockIdx.y;
    float* C = covb + (size_t)ml * NN * NN;
    int rowbase = p + blockIdx.x * 128;

    __shared__ __align__(16) float As[32][132];  // k-major, 128 rows (A slice)
    __shared__ __align__(16) float Bs[32][68];   // k-major, 64 rows  (B slice)

    int tid = threadIdx.x;
    int tx = tid & 7,  ty = tid >> 3;     // 8 col-groups x 32 row-groups
    int c0 = tx * 8,   r0 = ty * 4;

    float4 acc[4][2];
    #pragma unroll
    for (int r = 0; r < 4; ++r) { acc[r][0] = make_float4(0,0,0,0); acc[r][1] = make_float4(0,0,0,0); }

    for (int ks = 0; ks < p; ks += 32) {
        // stage A: 128 rows x 32 k
        for (int idx = tid; idx < 128 * 8; idx += 256) {
            int ii = idx >> 3;
            int c4 = (idx & 7) << 2;
            int gr = rowbase + ii;
            float4 v = make_float4(0,0,0,0);
            if (gr < NN) v = *(const float4*)(C + (size_t)gr * NN + ks + c4);
            As[c4+0][ii] = v.x; As[c4+1][ii] = v.y;
            As[c4+2][ii] = v.z; As[c4+3][ii] = v.w;
        }
        // stage B: 64 rows (the diag-block rows p..p+63) x 32 k
        for (int idx = tid; idx < 64 * 8; idx += 256) {
            int ii = idx >> 3;
            int c4 = (idx & 7) << 2;
            float4 v = *(const float4*)(C + (size_t)(p + ii) * NN + ks + c4);
            Bs[c4+0][ii] = v.x; Bs[c4+1][ii] = v.y;
            Bs[c4+2][ii] = v.z; Bs[c4+3][ii] = v.w;
        }
        __syncthreads();
        #pragma unroll
        for (int k = 0; k < 32; ++k) {
            float4 b0 = *(const float4*)&Bs[k][c0];
            float4 b1 = *(const float4*)&Bs[k][c0 + 4];
            float4 a0 = *(const float4*)&As[k][r0];
            float ar[4] = {a0.x, a0.y, a0.z, a0.w};
            #pragma unroll
            for (int r = 0; r < 4; ++r) {
                fma4(acc[r][0], ar[r], b0);
                fma4(acc[r][1], ar[r], b1);
            }
        }
        __syncthreads();
    }

    int jcol = p + c0;
    #pragma unroll
    for (int r = 0; r < 4; ++r) {
        int g = rowbase + r0 + r;
        if (g < NN) {
            float* cp = C + (size_t)g * NN + jcol;
            float4 u0 = *(float4*)cp;
            float4 u1 = *((float4*)cp + 1);
            u0.x -= acc[r][0].x; u0.y -= acc[r][0].y; u0.z -= acc[r][0].z; u0.w -= acc[r][0].w;
            u1.x -= acc[r][1].x; u1.y -= acc[r][1].y; u1.z -= acc[r][1].z; u1.w -= acc[r][1].w;
            *(float4*)cp = u0;
            *((float4*)cp + 1) = u1;
        }
    }
}

// ---------------- wave-register 64x64 diagonal factor + fused solve ----------------
__global__ __launch_bounds__(64)
void diag_kernel(float* __restrict__ covb, float* __restrict__ bvec,
                 float* __restrict__ rs_ws, float* __restrict__ sol_ws,
                 float* __restrict__ stats, float* __restrict__ out,
                 const float* __restrict__ scal, int mbase, int p)
{
    int ml = blockIdx.x;
    int m  = mbase + ml;
    int r  = threadIdx.x;
    float* C = covb + (size_t)ml * NN * NN;

    float row[NB];
    float* src = C + (size_t)(p + r) * NN + p;
    #pragma unroll
    for (int q = 0; q < NB/4; ++q) {
        float4 v = *(const float4*)(src + 4*q);
        row[4*q+0] = v.x; row[4*q+1] = v.y; row[4*q+2] = v.z; row[4*q+3] = v.w;
    }
    float b = bvec[(size_t)m * NN + p + r];
    float quad_add = 0.f, my_d = 1.f;
    #pragma unroll
    for (int j = 0; j < NB; ++j) {
        float dj = fmaxf(bcastf(row[j], j), 1e-30f);
        float rs = rsqrtf(dj);
        if (r == j) my_d = dj;
        row[j] *= rs;                       // row[j] = L[r][j] for r>=j
        float sj = bcastf(b, j) * rs;
        quad_add = fmaf(sj, sj, quad_add);
        b = fmaf(-row[j], sj, b);
        if (r == j) { rs_ws[m*NB + j] = rs; sol_ws[m*NB + j] = sj; }
        #pragma unroll
        for (int c = j + 1; c < NB; ++c) {
            float s = bcastf(row[j], c);    // = L[c][j]
            row[c] = fmaf(-row[j], s, row[c]);
        }
    }
    #pragma unroll
    for (int q = 0; q < NB/4; ++q) {
        float4 v; v.x = row[4*q]; v.y = row[4*q+1]; v.z = row[4*q+2]; v.w = row[4*q+3];
        *(float4*)(src + 4*q) = v;
    }
    float ldv = logf(my_d);
    #pragma unroll
    for (int off = 32; off > 0; off >>= 1) ldv += __shfl_down(ldv, off);
    if (r == 0) {
        float qt = stats[2*m]   + quad_add;
        float lt = stats[2*m+1] + ldv;
        stats[2*m] = qt; stats[2*m+1] = lt;
        if (p == NN - NB)
            out[m] = -0.5f * (qt + lt + (float)NN * LOG2PI) + scal[5*NSAMP + m];
    }
}

// ---------------- panel TRSM (parallel across row-tiles and samples) ----------------
__global__ __launch_bounds__(256)
void trsm_kernel(float* __restrict__ covb, float* __restrict__ bvec,
                 const float* __restrict__ rs_ws, const float* __restrict__ sol_ws,
                 int mbase, int p)
{
    int ml = blockIdx.y;
    int m  = mbase + ml;
    float* C = covb + (size_t)ml * NN * NN;
    __shared__ __align__(16) float Tl[NB][68];
    __shared__ float rs_s[NB], sol_s[NB];
    int tid = threadIdx.x;

    for (int idx = tid; idx < NB * (NB/4); idx += 256) {
        int rr = idx >> 4, c4 = (idx & 15) << 2;
        *(float4*)&Tl[rr][c4] = *(const float4*)(C + (size_t)(p + rr) * NN + p + c4);
    }
    if (tid < NB) { rs_s[tid] = rs_ws[m*NB + tid]; sol_s[tid] = sol_ws[m*NB + tid]; }
    __syncthreads();

    int r0 = p + NB + blockIdx.x * 256 + tid;
    if (r0 >= NN) return;
    float* rowp = C + (size_t)r0 * NN + p;
    float l[NB];
    #pragma unroll
    for (int q = 0; q < NB/4; ++q) {
        float4 v = *(const float4*)(rowp + 4*q);
        l[4*q] = v.x; l[4*q+1] = v.y; l[4*q+2] = v.z; l[4*q+3] = v.w;
    }
    #pragma unroll
    for (int j = 0; j < NB; ++j) {
        float acc = l[j];
        int c = 0;
        #pragma unroll
        for (; c + 4 <= j; c += 4) {
            float4 t = *(const float4*)&Tl[j][c];
            acc = fmaf(-l[c],   t.x, acc);
            acc = fmaf(-l[c+1], t.y, acc);
            acc = fmaf(-l[c+2], t.z, acc);
            acc = fmaf(-l[c+3], t.w, acc);
        }
        #pragma unroll
        for (; c < j; ++c) acc = fmaf(-l[c], Tl[j][c], acc);
        l[j] = acc * rs_s[j];
    }
    #pragma unroll
    for (int q = 0; q < NB/4; ++q) {
        float4 v; v.x = l[4*q]; v.y = l[4*q+1]; v.z = l[4*q+2]; v.w = l[4*q+3];
        *(float4*)(rowp + 4*q) = v;
    }
    float bacc = 0.f;
    #pragma unroll
    for (int j = 0; j < NB; ++j) bacc = fmaf(l[j], sol_s[j], bacc);
    bvec[(size_t)m * NN + r0] -= bacc;
}

extern "C" void kernel_launch(void* const* d_in, const int* in_sizes, int n_in,
                              void* d_out, int out_size, void* d_ws, size_t ws_size,
                              hipStream_t stream)
{
    const float* x   = (const float*)d_in[0];
    const float* y   = (const float*)d_in[1];
    const float* z   = (const float*)d_in[2];
    const float* qbm = (const float*)d_in[3];
    const float* qbs = (const float*)d_in[4];
    const float* qsm = (const float*)d_in[5];
    const float* qss = (const float*)d_in[6];
    const float* qem = (const float*)d_in[7];
    const float* qes = (const float*)d_in[8];
    const float* qzm = (const float*)d_in[9];
    const float* qzs = (const float*)d_in[10];
    const float* qnm = (const float*)d_in[11];
    const float* qns = (const float*)d_in[12];
    float* out  = (float*)d_out;
    float* ws   = (float*)d_ws;

    // workspace layout (floats)
    float* scal   = ws;                                   // 384 used
    float* bvec   = ws + 1024;                            // 64*1024
    float* stats  = ws + 1024 + NSAMP*NN;                 // 128 used, 512 res
    float* rs_ws  = ws + 1024 + NSAMP*NN + 512;           // 64*64
    float* sol_ws = ws + 1024 + NSAMP*NN + 512 + NSAMP*NB;
    float* cov    = ws + 1024 + NSAMP*NN + 512 + 2*NSAMP*NB;
    size_t headF  = 1024 + (size_t)NSAMP*NN + 512 + 2*(size_t)NSAMP*NB;

    scal_kernel<<<1, 64, 0, stream>>>(z, qbm, qbs, qsm, qss, qem, qes, qzm, qzs, qnm, qns, scal);

    size_t availF = ws_size / 4;
    size_t perM   = (size_t)NN * NN;
    int mc_max = NSAMP;
    if (availF < headF + (size_t)NSAMP * perM) {
        size_t rem = (availF > headF) ? (availF - headF) : 0;
        mc_max = (int)(rem / perM);
        if (mc_max < 1) mc_max = 1;
        if (mc_max > NSAMP) mc_max = NSAMP;
    }

    for (int mb = 0; mb < NSAMP; mb += mc_max) {
        int mc = NSAMP - mb; if (mc > mc_max) mc = mc_max;
        cov_kernel<<<dim3(NN, mc), 256, 0, stream>>>(cov, scal, x, y, bvec, stats, mb);
        for (int q = 0; q < NN / NB; ++q) {
            int p = q * NB;
            if (q > 0) {
                int rows = NN - p;
                int rt = (rows + 127) / 128;
                update_kernel<<<dim3(rt, mc), 256, 0, stream>>>(cov, p);
            }
            diag_kernel<<<mc, 64, 0, stream>>>(cov, bvec, rs_ws, sol_ws, stats, out, scal, mb, p);
            int rb = NN - p - NB;
            if (rb > 0) {
                int rtiles = (rb + 255) / 256;
                trsm_kernel<<<dim3(rtiles, mc), 256, 0, stream>>>(cov, bvec, rs_ws, sol_ws, mb, p);
            }
        }
    }
}